// Round 8
// baseline (205.516 us; speedup 1.0000x reference)
//
#include <hip/hip_runtime.h>
#include <stdint.h>

// MultiHeadsSelfAttention: B=2, N=2048, C=1024, H=16, D=64, SCALE=0.125
// fp16 MFMA, fp32 accum/softmax.
//   cvt_all: x,W* -> fp16 (one launch)
//   gemm_qkv / gemm_out: NT GEMMs, R8: issue-early double-buffered K-loop —
//         { __syncthreads; stage(k+1) -> other slot; compute(k) }. The barrier
//         at step k drains stage(k) issued one full compute-phase earlier, so
//         DMA latency hides under MFMA. (Old code staged then immediately
//         drained: zero overlap, 16x per GEMM.) qkv LDS 64 KB (256,2);
//         out LDS 48 KB (256,3).
//   attn: R5 config EXACTLY (best measured: 46.0 us). 8 structural variants
//         R0-R7 all landed 45-49 us: occupancy 2x (+7%), counted-vmcnt (+1%),
//         LDS reads halved (0%), L2/XCD locality (FETCH 69.7->12.3 MB, 0%),
//         all-wave delay (-6%), parity stagger (-5%). Structure is at its
//         floor; do not touch without a new mechanism.
//         FAT-WAVE: 4 waves = 2 qgroups x 2 key parities, 64 q-rows/wave;
//         every kf/vf LDS read feeds both q-subtiles' MFMAs. XCD-bijective
//         block swizzle keeps per-XCD K/V at 2 MB (L2-resident). 3-slot
//         rotation staged 2 ahead, `s_waitcnt vmcnt(4); s_barrier`.
//         __launch_bounds__(256,2) — R2 lesson: tighter min-waves caps VGPR
//         and spills catastrophically.
//         K staged with f(row)=(row&3)|((row>>1)&4) chunk swizzle matching the
//         bit2<->bit3 krow read permutation; V with row&7.
//         S^T operand-swap => P packs in-register (pkrtz of consecutive C
//         regs) into the PV B-operand. No-max exp2 softmax; parity partials
//         combine by plain addition through LDS.

typedef _Float16 h8 __attribute__((ext_vector_type(8)));
typedef _Float16 h4 __attribute__((ext_vector_type(4)));
typedef float f4 __attribute__((ext_vector_type(4)));
typedef float f16f __attribute__((ext_vector_type(16)));
typedef uint32_t u32;
typedef u32 u32x4 __attribute__((ext_vector_type(4)));

#define AS1(p) ((const __attribute__((address_space(1))) void*)(p))
#define AS3(p) ((__attribute__((address_space(3))) void*)(p))

// Stage ITERS*32 rows of 128 B (8 x 16B chunks, XOR swizzle ch^(row&7)), 256 thr.
template <int ITERS>
__device__ __forceinline__ void stage128B(const _Float16* g, int ldk, _Float16* s, int tid) {
#pragma unroll
  for (int j = 0; j < ITERS; ++j) {
    int off = j * 4096 + tid * 16;
    int row = off >> 7;
    int ch = (off >> 4) & 7;
    int gch = ch ^ (row & 7);
    __builtin_amdgcn_global_load_lds(AS1(g + row * ldk + gch * 8), AS3(s + (off >> 1)), 16, 0, 0);
  }
}

// attn staging, 256 thr, 64 rows x 128 B (2 x 16B chunks per thread).
// V: swizzle ch^(row&7) — read rows are l31 directly.
__device__ __forceinline__ void stage_v(const _Float16* g, _Float16* s, int tid) {
#pragma unroll
  for (int j = 0; j < 2; ++j) {
    int off = j * 4096 + tid * 16;   // 0..8191
    int row = off >> 7;              // 0..63
    int ch = (off >> 4) & 7;
    int gch = ch ^ (row & 7);
    __builtin_amdgcn_global_load_lds(AS1(g + row * 2048 + gch * 8), AS3(s + (off >> 1)), 16, 0, 0);
  }
}
// K: swizzle ch^f(row), f = bits{0,1,3} of row, matching the krow (bit2<->bit3)
// read permutation.
__device__ __forceinline__ void stage_k(const _Float16* g, _Float16* s, int tid) {
#pragma unroll
  for (int j = 0; j < 2; ++j) {
    int off = j * 4096 + tid * 16;
    int row = off >> 7;
    int ch = (off >> 4) & 7;
    int gch = ch ^ ((row & 3) | ((row >> 1) & 4));
    __builtin_amdgcn_global_load_lds(AS1(g + row * 64 + gch * 8), AS3(s + (off >> 1)), 16, 0, 0);
  }
}

__device__ __forceinline__ h8 frag64(const _Float16* s, int row, int g) {
  return *(const h8*)(s + row * 64 + ((g ^ (row & 7)) << 3));
}

// One fused cast kernel: x (4096 blk) + Wq/Wk/Wv/Wo (1024 blk each).
__global__ void cvt_all(const float* __restrict__ x, const float* __restrict__ Wq,
                        const float* __restrict__ Wk, const float* __restrict__ Wv,
                        const float* __restrict__ Wo, _Float16* __restrict__ xh,
                        _Float16* __restrict__ q, _Float16* __restrict__ k,
                        _Float16* __restrict__ v, _Float16* __restrict__ o) {
  int blk = blockIdx.x;
  const float* src; _Float16* dst; int off;
  if (blk < 4096)      { src = x;  dst = xh; off = blk; }
  else if (blk < 5120) { src = Wq; dst = q;  off = blk - 4096; }
  else if (blk < 6144) { src = Wk; dst = k;  off = blk - 5120; }
  else if (blk < 7168) { src = Wv; dst = v;  off = blk - 6144; }
  else                 { src = Wo; dst = o;  off = blk - 7168; }
  int i = off * 1024 + threadIdx.x * 4;
  f4 vv = *(const f4*)(src + i);
  h4 ov;
  ov[0] = (_Float16)vv[0]; ov[1] = (_Float16)vv[1]; ov[2] = (_Float16)vv[2]; ov[3] = (_Float16)vv[3];
  *(h4*)(dst + i) = ov;
}

// NT GEMM x@W^T+b. z=0: Q scaled by SCALE*log2e -> [bh][n][d]; z=1: K -> [bh][n][d];
// z=2: V written directly transposed -> Vt [bh][d][n] (b64 stores).
// R8: double-buffered K-loop, stage(k+1) issued AFTER the barrier so its DMA
// overlaps compute(k). Slot (k+1)&1 was last read at compute(k-1), sealed by
// this barrier; barrier's vmcnt(0) drain guarantees stage(k) complete.
__global__ __launch_bounds__(256, 2) void gemm_qkv(
    const _Float16* __restrict__ X,
    const _Float16* __restrict__ W0, const _Float16* __restrict__ W1, const _Float16* __restrict__ W2,
    const float* __restrict__ b0, const float* __restrict__ b1, const float* __restrict__ b2,
    _Float16* __restrict__ O0, _Float16* __restrict__ O1, _Float16* __restrict__ O2) {
  __shared__ _Float16 As[2][128 * 64];
  __shared__ _Float16 Bs[2][128 * 64];
  int z = blockIdx.z;
  const _Float16* W = (z == 0) ? W0 : (z == 1) ? W1 : W2;
  const float* bias = (z == 0) ? b0 : (z == 1) ? b1 : b2;

  int tid = threadIdx.x;
  int lane = tid & 63, wave = tid >> 6;
  int quad = lane >> 4, l15 = lane & 15;
  int wm = (wave >> 1) << 6, wn = (wave & 1) << 6;
  int m0 = blockIdx.y << 7, n0 = blockIdx.x << 7;

  stage128B<4>(X + m0 * 1024, 1024, As[0], tid);
  stage128B<4>(W + n0 * 1024, 1024, Bs[0], tid);

  f4 acc[4][4] = {};
  for (int k = 0; k < 16; ++k) {
    __syncthreads();   // drains stage(k) DMA (issued last iter) + seals slot reuse
    if (k < 15) {
      stage128B<4>(X + m0 * 1024 + (k + 1) * 64, 1024, As[(k + 1) & 1], tid);
      stage128B<4>(W + n0 * 1024 + (k + 1) * 64, 1024, Bs[(k + 1) & 1], tid);
    }
    const _Float16* Asl = As[k & 1];
    const _Float16* Bsl = Bs[k & 1];
#pragma unroll
    for (int ks = 0; ks < 2; ++ks) {
      h8 af[4], bf[4];
#pragma unroll
      for (int i = 0; i < 4; ++i) af[i] = frag64(Asl, wm + i * 16 + l15, ks * 4 + quad);
#pragma unroll
      for (int i = 0; i < 4; ++i) bf[i] = frag64(Bsl, wn + i * 16 + l15, ks * 4 + quad);
#pragma unroll
      for (int mi = 0; mi < 4; ++mi)
#pragma unroll
        for (int ni = 0; ni < 4; ++ni)
          acc[mi][ni] = __builtin_amdgcn_mfma_f32_16x16x32_f16(af[mi], bf[ni], acc[mi][ni], 0, 0, 0);
    }
  }

  if (z == 2) {
#pragma unroll
    for (int mi = 0; mi < 4; ++mi) {
#pragma unroll
      for (int ni = 0; ni < 4; ++ni) {
        int o = n0 + wn + ni * 16 + l15;
        float bv = bias[o];
        int h = o >> 6, dd = o & 63;
        int m = m0 + wm + mi * 16 + quad * 4;
        int b = m >> 11, n = m & 2047;
        h4 v;
#pragma unroll
        for (int r = 0; r < 4; ++r) v[r] = (_Float16)(acc[mi][ni][r] + bv);
        *(h4*)(O2 + (((b * 16 + h) * 64 + dd) * 2048 + n)) = v;
      }
    }
  } else {
    float scale = (z == 0) ? 0.125f * 1.44269504089f : 1.0f;
    _Float16* Out = (z == 0) ? O0 : O1;
#pragma unroll
    for (int mi = 0; mi < 4; ++mi) {
#pragma unroll
      for (int ni = 0; ni < 4; ++ni) {
        int o = n0 + wn + ni * 16 + l15;
        float bv = bias[o];
        int h = o >> 6, d = o & 63;
#pragma unroll
        for (int r = 0; r < 4; ++r) {
          int m = m0 + wm + mi * 16 + quad * 4 + r;
          int b = m >> 11, n = m & 2047;
          float v = (acc[mi][ni][r] + bv) * scale;
          Out[(((b * 16 + h) * 2048 + n) << 6) + d] = (_Float16)v;
        }
      }
    }
  }
}

// Final NT GEMM 128x64 tiles (512 blocks): out fp32 [m][1024].
// R8: same issue-early double-buffer as gemm_qkv. 48 KB LDS -> 3 blocks/CU.
__global__ __launch_bounds__(256, 3) void gemm_out(
    const _Float16* __restrict__ A, const _Float16* __restrict__ W,
    const float* __restrict__ bias, float* __restrict__ Out) {
  __shared__ _Float16 As[2][128 * 64];
  __shared__ _Float16 Bs[2][64 * 64];
  int tid = threadIdx.x;
  int lane = tid & 63, wave = tid >> 6;
  int quad = lane >> 4, l15 = lane & 15;
  int wm = (wave >> 1) << 6, wn = (wave & 1) << 5;
  int m0 = blockIdx.y << 7, n0 = blockIdx.x << 6;

  stage128B<4>(A + m0 * 1024, 1024, As[0], tid);
  stage128B<2>(W + n0 * 1024, 1024, Bs[0], tid);

  f4 acc[4][2] = {};
  for (int k = 0; k < 16; ++k) {
    __syncthreads();
    if (k < 15) {
      stage128B<4>(A + m0 * 1024 + (k + 1) * 64, 1024, As[(k + 1) & 1], tid);
      stage128B<2>(W + n0 * 1024 + (k + 1) * 64, 1024, Bs[(k + 1) & 1], tid);
    }
    const _Float16* Asl = As[k & 1];
    const _Float16* Bsl = Bs[k & 1];
#pragma unroll
    for (int ks = 0; ks < 2; ++ks) {
      h8 af[4], bf[2];
#pragma unroll
      for (int i = 0; i < 4; ++i) af[i] = frag64(Asl, wm + i * 16 + l15, ks * 4 + quad);
#pragma unroll
      for (int i = 0; i < 2; ++i) bf[i] = frag64(Bsl, wn + i * 16 + l15, ks * 4 + quad);
#pragma unroll
      for (int mi = 0; mi < 4; ++mi)
#pragma unroll
        for (int ni = 0; ni < 2; ++ni)
          acc[mi][ni] = __builtin_amdgcn_mfma_f32_16x16x32_f16(af[mi], bf[ni], acc[mi][ni], 0, 0, 0);
    }
  }
#pragma unroll
  for (int mi = 0; mi < 4; ++mi) {
#pragma unroll
    for (int ni = 0; ni < 2; ++ni) {
      int o = n0 + wn + ni * 16 + l15;
      float bv = bias[o];
#pragma unroll
      for (int r = 0; r < 4; ++r) {
        int m = m0 + wm + mi * 16 + quad * 4 + r;
        Out[m * 1024 + o] = acc[mi][ni][r] + bv;
      }
    }
  }
}

// Flash attention, 32x32x16 MFMA. Grid (16, 32), 256 threads. R5 config.
// 4 FAT waves: qg = wave>>1 (2 x 64 qrows = 128 rows/block), parity p = wave&1.
// Each wave: 64 q-rows as 2 q-subtiles (qsub*32 + l31); every kf/vf LDS read
// feeds BOTH q-subtiles' MFMAs. Wave p computes key tiles t with t&1==p.
// Tiles staged as 64-key PAIRS (K: [64 keys][64 d] swizzle f(row), V:
// [64 d][64 keys] swizzle row&7) into 3 rotating slots, staged 2 AHEAD.
// Phase barrier `s_waitcnt vmcnt(4); s_barrier`: drains pair ph (my 4 oldest
// DMAs), pair ph+1's 4 stay in flight. Stage of pair ph+2 issued AFTER
// compute(ph) — its slot was last read at phase ph-1, sealed by barrier(ph).
// QK: S^T = K.Q^T; kf A-row m holds key = swapbits23(m), so C-layout
// (row=(reg&3)+8*(reg>>2)+4h, col=l31) gives lane h keys {s*16+h*8+j}: reg pairs
// (2i,2i+1) pack via cvt_pkrtz into PV B-operand pb[s]=pkw[4s..4s+3].
// PV: O^T = Vt.P^T (A = Vt d-rows). No online max (exp2 raw) => parity
// partials combine by plain addition through LDS at the end.
__global__ __launch_bounds__(256, 2) void attn(
    const _Float16* __restrict__ Q, const _Float16* __restrict__ Kv,
    const _Float16* __restrict__ Vt, _Float16* __restrict__ AO) {
  __shared__ _Float16 smem[6 * 4096];   // 48 KB: Ks[3] | Vs[3]
  _Float16* Ksb = smem;
  _Float16* Vsb = smem + 3 * 4096;

  int tid = threadIdx.x, lane = tid & 63, wave = tid >> 6;
  int h = lane >> 5, l31 = lane & 31;
  int p = wave & 1, qg = wave >> 1;

  // XCD-aware bijective remap (512 blocks, 8 XCDs): blocks on one XCD cover
  // 4 consecutive bh -> 2 MB K/V fits per-XCD L2 (R5: FETCH 69.7->12.3 MB).
  int flat = blockIdx.y * 16 + blockIdx.x;
  int nid = (flat & 7) * 64 + (flat >> 3);
  int bh = nid >> 4, q0 = (nid & 15) << 7;

  // qf[qsub]: B[k][n=qrow=l31], dk = ks4*16 + h*8 + j; qrows = q0+qg*64+qsub*32+l31
  const _Float16* Qb = Q + (bh * 2048 + q0 + qg * 64 + l31) * 64;
  h8 qf[2][4];
#pragma unroll
  for (int qs = 0; qs < 2; ++qs)
#pragma unroll
    for (int ks4 = 0; ks4 < 4; ++ks4)
      qf[qs][ks4] = *(const h8*)(Qb + qs * 32 * 64 + ks4 * 16 + h * 8);

  // key-row permutation: swap bits 2<->3 of C-row index
  int krow = (l31 & 19) | ((l31 & 4) << 1) | ((l31 & 8) >> 1);
  int kbase = (p * 32 + krow) * 64;   // my 32-key subtile within the 64-row pair
  int kx = (krow & 3) | ((krow >> 1) & 4);   // f(krow): matches stage_k swizzle
  int vx = l31 & 7;

  const _Float16* Kb = Kv + bh * 131072;
  const _Float16* Vb = Vt + bh * 131072;
  f16f oacc[2][2] = {};   // [qsub][dt]
  float lsum[2] = {0.f, 0.f};

  // prologue: stage pairs 0 (slot 0) and 1 (slot 1); 8 DMAs/thread outstanding
  stage_k(Kb, Ksb, tid);
  stage_v(Vb, Vsb, tid);
  stage_k(Kb + 4096, Ksb + 4096, tid);
  stage_v(Vb + 64, Vsb + 4096, tid);

  int bp = 0;   // slot of current pair = ph % 3
  for (int ph = 0; ph < 32; ++ph) {
    // Counted-vmcnt barrier: pair ph's 4 DMAs (my oldest) drained; pair ph+1's
    // 4 stay in flight across the barrier.
    if (ph < 31) {
      asm volatile("s_waitcnt vmcnt(4)\n\ts_barrier" ::: "memory");
    } else {
      asm volatile("s_waitcnt vmcnt(0)\n\ts_barrier" ::: "memory");
    }
    const _Float16* Kst = Ksb + bp * 4096;
    const _Float16* Vst = Vsb + bp * 4096;

    // QK: my 32-key subtile x 64 qrows (2 subtiles), K-dim 64 in 4 steps of 16.
    f16f sacc[2] = {};
#pragma unroll
    for (int ks4 = 0; ks4 < 4; ++ks4) {
      h8 kf = *(const h8*)(Kst + kbase + (((ks4 * 2 + h) ^ kx) << 3));
      sacc[0] = __builtin_amdgcn_mfma_f32_32x32x16_f16(kf, qf[0][ks4], sacc[0], 0, 0, 0);
      sacc[1] = __builtin_amdgcn_mfma_f32_32x32x16_f16(kf, qf[1][ks4], sacc[1], 0, 0, 0);
    }

    // P = exp2(s) raw; consecutive C regs pair into PV B-operand halves.
    u32 pkw[2][8];
#pragma unroll
    for (int qs = 0; qs < 2; ++qs) {
#pragma unroll
      for (int i = 0; i < 8; ++i) {
        float pa = __builtin_amdgcn_exp2f(sacc[qs][2 * i]);
        float pb = __builtin_amdgcn_exp2f(sacc[qs][2 * i + 1]);
        lsum[qs] += pa + pb;
        pkw[qs][i] = __builtin_bit_cast(u32, __builtin_amdgcn_cvt_pkrtz(pa, pb));
      }
    }

    // PV: O^T += Vt . P^T over 2 ksteps of 16 keys, d in 2 subtiles.
#pragma unroll
    for (int s = 0; s < 2; ++s) {
      u32x4 pw0 = {pkw[0][4 * s], pkw[0][4 * s + 1], pkw[0][4 * s + 2], pkw[0][4 * s + 3]};
      u32x4 pw1 = {pkw[1][4 * s], pkw[1][4 * s + 1], pkw[1][4 * s + 2], pkw[1][4 * s + 3]};
      h8 pb0 = __builtin_bit_cast(h8, pw0);
      h8 pb1 = __builtin_bit_cast(h8, pw1);
      int ch = (((p << 2) | (s << 1) | h) ^ vx) << 3;
#pragma unroll
      for (int dt = 0; dt < 2; ++dt) {
        h8 vf = *(const h8*)(Vst + (dt * 32 + l31) * 64 + ch);
        oacc[0][dt] = __builtin_amdgcn_mfma_f32_32x32x16_f16(vf, pb0, oacc[0][dt], 0, 0, 0);
        oacc[1][dt] = __builtin_amdgcn_mfma_f32_32x32x16_f16(vf, pb1, oacc[1][dt], 0, 0, 0);
      }
    }

    // Stage pair ph+2 into slot (bp+2)%3 (last read at phase ph-1, sealed by
    // barrier(ph) above).
    if (ph < 30) {
      int sl = bp ? bp - 1 : 2;
      stage_k(Kb + (ph + 2) * 4096, Ksb + sl * 4096, tid);
      stage_v(Vb + (ph + 2) * 64, Vsb + sl * 4096, tid);
    }
    bp = (bp == 2) ? 0 : bp + 1;
  }

  // Combine parity partials (plain addition: no-max softmax) through LDS.
  __syncthreads();   // all compute + DMA done; smem free for reuse
  float* cb = (float*)smem;   // 2 odd waves x 64 lanes x 66 floats = 33792 B
  if (p) {
    float* w = cb + (qg * 64 + lane) * 66;
#pragma unroll
    for (int qs = 0; qs < 2; ++qs)
#pragma unroll
      for (int dt = 0; dt < 2; ++dt)
#pragma unroll
        for (int i = 0; i < 16; ++i) w[(qs * 2 + dt) * 16 + i] = oacc[qs][dt][i];
    w[64] = lsum[0];
    w[65] = lsum[1];
  }
  __syncthreads();
  if (!p) {
    const float* r = cb + (qg * 64 + lane) * 66;
#pragma unroll
    for (int qs = 0; qs < 2; ++qs)
#pragma unroll
      for (int dt = 0; dt < 2; ++dt)
#pragma unroll
        for (int i = 0; i < 16; ++i) oacc[qs][dt][i] += r[(qs * 2 + dt) * 16 + i];
    lsum[0] += r[64];
    lsum[1] += r[65];

    // Epilogue: col = qrow = l31 for all oacc; rows d = dt*32 + 8*b2 + 4h + a.
    int b = bh >> 4, hh = bh & 15;
#pragma unroll
    for (int qs = 0; qs < 2; ++qs) {
      float l = lsum[qs] + __shfl_xor(lsum[qs], 32);
      float inv = 1.0f / l;
      int n = q0 + qg * 64 + qs * 32 + l31;
      _Float16* base = AO + (b * 2048 + n) * 1024 + hh * 64;
#pragma unroll
      for (int dt = 0; dt < 2; ++dt) {
#pragma unroll
        for (int b2 = 0; b2 < 4; ++b2) {
          h4 o;
#pragma unroll
          for (int a = 0; a < 4; ++a) o[a] = (_Float16)(oacc[qs][dt][b2 * 4 + a] * inv);
          *(h4*)(base + dt * 32 + b2 * 8 + h * 4) = o;
        }
      }
    }
  }
}

extern "C" void kernel_launch(void* const* d_in, const int* in_sizes, int n_in,
                              void* d_out, int out_size, void* d_ws, size_t ws_size,
                              hipStream_t stream) {
  const float* x = (const float*)d_in[0];
  const float* Wq = (const float*)d_in[1];
  const float* bq = (const float*)d_in[2];
  const float* Wk = (const float*)d_in[3];
  const float* bk = (const float*)d_in[4];
  const float* Wv = (const float*)d_in[5];
  const float* bv = (const float*)d_in[6];
  const float* Wo = (const float*)d_in[7];
  const float* bo = (const float*)d_in[8];
  float* out = (float*)d_out;

  char* w = (char*)d_ws;
  _Float16* xh  = (_Float16*)(w);                // 8 MB (reused as AO after gemm_qkv)
  _Float16* Wqh = (_Float16*)(w + (8u << 20));   // 2 MB each
  _Float16* Wkh = (_Float16*)(w + (10u << 20));
  _Float16* Wvh = (_Float16*)(w + (12u << 20));
  _Float16* Woh = (_Float16*)(w + (14u << 20));
  _Float16* Qh  = (_Float16*)(w + (16u << 20));  // 8 MB each
  _Float16* Kh  = (_Float16*)(w + (24u << 20));
  _Float16* Vth = (_Float16*)(w + (32u << 20));
  _Float16* AOh = xh;

  cvt_all<<<8192, 256, 0, stream>>>(x, Wq, Wk, Wv, Wo, xh, Wqh, Wkh, Wvh, Woh);
  gemm_qkv<<<dim3(8, 32, 3), 256, 0, stream>>>(xh, Wqh, Wkh, Wvh, bq, bk, bv, Qh, Kh, Vth);
  attn<<<dim3(16, 32), 256, 0, stream>>>(Qh, Kh, Vth, AOh);
  gemm_out<<<dim3(16, 32), 256, 0, stream>>>(AOh, Woh, bo, out);
}

// Round 9
// 175.408 us; speedup vs baseline: 1.1716x; 1.1716x over previous
//
#include <hip/hip_runtime.h>
#include <stdint.h>

// MultiHeadsSelfAttention: B=2, N=2048, C=1024, H=16, D=64, SCALE=0.125
// fp16 MFMA, fp32 accum/softmax.
//   cvt_all: x,W* -> fp16 (one launch, 8 f32/thread: 32B read/16B write per lane)
//   gemm_qkv / gemm_out: NT GEMMs, single-buffered stage->sync->compute->sync,
//         __launch_bounds__(256,3), 32/24 KB LDS -> ~4 blocks/CU. R8 LESSON:
//         double-buffering (64 KB LDS, 2 blocks/CU) regressed qkv 38->63 us —
//         for small-tile GEMMs cross-block TLP already hides staging latency;
//         occupancy is the binding constraint, never trade it for pipeline depth.
//   attn: R5 config EXACTLY (best measured: 46.0 us). 8 structural variants
//         R0-R7 all landed 45-49 us: occupancy 2x (+7%), counted-vmcnt (+1%),
//         LDS reads halved (0%), L2/XCD locality (FETCH 69.7->12.3 MB, 0%),
//         all-wave delay (-6%), parity stagger (-5%). Structure is at its
//         floor; do not touch without a new mechanism.
//         FAT-WAVE: 4 waves = 2 qgroups x 2 key parities, 64 q-rows/wave;
//         every kf/vf LDS read feeds both q-subtiles' MFMAs. XCD-bijective
//         block swizzle keeps per-XCD K/V at 2 MB (L2-resident). 3-slot
//         rotation staged 2 ahead, `s_waitcnt vmcnt(4); s_barrier`.
//         __launch_bounds__(256,2) — R2 lesson: tighter min-waves caps VGPR
//         and spills catastrophically (R2: VGPR 32, FETCH 69->295 MB, 3.4x).
//         K staged with f(row)=(row&3)|((row>>1)&4) chunk swizzle matching the
//         bit2<->bit3 krow read permutation; V with row&7.
//         S^T operand-swap => P packs in-register (pkrtz of consecutive C
//         regs) into the PV B-operand. No-max exp2 softmax; parity partials
//         combine by plain addition through LDS.

typedef _Float16 h8 __attribute__((ext_vector_type(8)));
typedef _Float16 h4 __attribute__((ext_vector_type(4)));
typedef float f4 __attribute__((ext_vector_type(4)));
typedef float f16f __attribute__((ext_vector_type(16)));
typedef uint32_t u32;
typedef u32 u32x4 __attribute__((ext_vector_type(4)));

#define AS1(p) ((const __attribute__((address_space(1))) void*)(p))
#define AS3(p) ((__attribute__((address_space(3))) void*)(p))

// Stage ITERS*32 rows of 128 B (8 x 16B chunks, XOR swizzle ch^(row&7)), 256 thr.
template <int ITERS>
__device__ __forceinline__ void stage128B(const _Float16* g, int ldk, _Float16* s, int tid) {
#pragma unroll
  for (int j = 0; j < ITERS; ++j) {
    int off = j * 4096 + tid * 16;
    int row = off >> 7;
    int ch = (off >> 4) & 7;
    int gch = ch ^ (row & 7);
    __builtin_amdgcn_global_load_lds(AS1(g + row * ldk + gch * 8), AS3(s + (off >> 1)), 16, 0, 0);
  }
}

// attn staging, 256 thr, 64 rows x 128 B (2 x 16B chunks per thread).
// V: swizzle ch^(row&7) — read rows are l31 directly.
__device__ __forceinline__ void stage_v(const _Float16* g, _Float16* s, int tid) {
#pragma unroll
  for (int j = 0; j < 2; ++j) {
    int off = j * 4096 + tid * 16;   // 0..8191
    int row = off >> 7;              // 0..63
    int ch = (off >> 4) & 7;
    int gch = ch ^ (row & 7);
    __builtin_amdgcn_global_load_lds(AS1(g + row * 2048 + gch * 8), AS3(s + (off >> 1)), 16, 0, 0);
  }
}
// K: swizzle ch^f(row), f = bits{0,1,3} of row, matching the krow (bit2<->bit3)
// read permutation.
__device__ __forceinline__ void stage_k(const _Float16* g, _Float16* s, int tid) {
#pragma unroll
  for (int j = 0; j < 2; ++j) {
    int off = j * 4096 + tid * 16;
    int row = off >> 7;
    int ch = (off >> 4) & 7;
    int gch = ch ^ ((row & 3) | ((row >> 1) & 4));
    __builtin_amdgcn_global_load_lds(AS1(g + row * 64 + gch * 8), AS3(s + (off >> 1)), 16, 0, 0);
  }
}

__device__ __forceinline__ h8 frag64(const _Float16* s, int row, int g) {
  return *(const h8*)(s + row * 64 + ((g ^ (row & 7)) << 3));
}

// One fused cast kernel, 8 f32/thread: x (2048 blk) + Wq/Wk/Wv/Wo (512 blk each).
__global__ void cvt_all(const float* __restrict__ x, const float* __restrict__ Wq,
                        const float* __restrict__ Wk, const float* __restrict__ Wv,
                        const float* __restrict__ Wo, _Float16* __restrict__ xh,
                        _Float16* __restrict__ q, _Float16* __restrict__ k,
                        _Float16* __restrict__ v, _Float16* __restrict__ o) {
  int blk = blockIdx.x;
  const float* src; _Float16* dst; int off;
  if (blk < 2048)      { src = x;  dst = xh; off = blk; }
  else if (blk < 2560) { src = Wq; dst = q;  off = blk - 2048; }
  else if (blk < 3072) { src = Wk; dst = k;  off = blk - 2560; }
  else if (blk < 3584) { src = Wv; dst = v;  off = blk - 3072; }
  else                 { src = Wo; dst = o;  off = blk - 3584; }
  int i = off * 2048 + threadIdx.x * 8;
  f4 a = *(const f4*)(src + i);
  f4 b = *(const f4*)(src + i + 4);
  h8 ov;
  ov[0] = (_Float16)a[0]; ov[1] = (_Float16)a[1]; ov[2] = (_Float16)a[2]; ov[3] = (_Float16)a[3];
  ov[4] = (_Float16)b[0]; ov[5] = (_Float16)b[1]; ov[6] = (_Float16)b[2]; ov[7] = (_Float16)b[3];
  *(h8*)(dst + i) = ov;
}

// NT GEMM x@W^T+b. z=0: Q scaled by SCALE*log2e -> [bh][n][d]; z=1: K -> [bh][n][d];
// z=2: V written directly transposed -> Vt [bh][d][n] (b64 stores).
__global__ __launch_bounds__(256, 3) void gemm_qkv(
    const _Float16* __restrict__ X,
    const _Float16* __restrict__ W0, const _Float16* __restrict__ W1, const _Float16* __restrict__ W2,
    const float* __restrict__ b0, const float* __restrict__ b1, const float* __restrict__ b2,
    _Float16* __restrict__ O0, _Float16* __restrict__ O1, _Float16* __restrict__ O2) {
  __shared__ _Float16 As[128 * 64];
  __shared__ _Float16 Bs[128 * 64];
  int z = blockIdx.z;
  const _Float16* W = (z == 0) ? W0 : (z == 1) ? W1 : W2;
  const float* bias = (z == 0) ? b0 : (z == 1) ? b1 : b2;

  int tid = threadIdx.x;
  int lane = tid & 63, wave = tid >> 6;
  int quad = lane >> 4, l15 = lane & 15;
  int wm = (wave >> 1) << 6, wn = (wave & 1) << 6;
  int m0 = blockIdx.y << 7, n0 = blockIdx.x << 7;

  f4 acc[4][4] = {};
  for (int k0 = 0; k0 < 1024; k0 += 64) {
    stage128B<4>(X + m0 * 1024 + k0, 1024, As, tid);
    stage128B<4>(W + n0 * 1024 + k0, 1024, Bs, tid);
    __syncthreads();
#pragma unroll
    for (int ks = 0; ks < 2; ++ks) {
      h8 af[4], bf[4];
#pragma unroll
      for (int i = 0; i < 4; ++i) af[i] = frag64(As, wm + i * 16 + l15, ks * 4 + quad);
#pragma unroll
      for (int i = 0; i < 4; ++i) bf[i] = frag64(Bs, wn + i * 16 + l15, ks * 4 + quad);
#pragma unroll
      for (int mi = 0; mi < 4; ++mi)
#pragma unroll
        for (int ni = 0; ni < 4; ++ni)
          acc[mi][ni] = __builtin_amdgcn_mfma_f32_16x16x32_f16(af[mi], bf[ni], acc[mi][ni], 0, 0, 0);
    }
    __syncthreads();
  }

  if (z == 2) {
#pragma unroll
    for (int mi = 0; mi < 4; ++mi) {
#pragma unroll
      for (int ni = 0; ni < 4; ++ni) {
        int o = n0 + wn + ni * 16 + l15;
        float bv = bias[o];
        int h = o >> 6, dd = o & 63;
        int m = m0 + wm + mi * 16 + quad * 4;
        int b = m >> 11, n = m & 2047;
        h4 v;
#pragma unroll
        for (int r = 0; r < 4; ++r) v[r] = (_Float16)(acc[mi][ni][r] + bv);
        *(h4*)(O2 + (((b * 16 + h) * 64 + dd) * 2048 + n)) = v;
      }
    }
  } else {
    float scale = (z == 0) ? 0.125f * 1.44269504089f : 1.0f;
    _Float16* Out = (z == 0) ? O0 : O1;
#pragma unroll
    for (int mi = 0; mi < 4; ++mi) {
#pragma unroll
      for (int ni = 0; ni < 4; ++ni) {
        int o = n0 + wn + ni * 16 + l15;
        float bv = bias[o];
        int h = o >> 6, d = o & 63;
#pragma unroll
        for (int r = 0; r < 4; ++r) {
          int m = m0 + wm + mi * 16 + quad * 4 + r;
          int b = m >> 11, n = m & 2047;
          float v = (acc[mi][ni][r] + bv) * scale;
          Out[(((b * 16 + h) * 2048 + n) << 6) + d] = (_Float16)v;
        }
      }
    }
  }
}

// Final NT GEMM 128x64 tiles (512 blocks): out fp32 [m][1024].
__global__ __launch_bounds__(256, 3) void gemm_out(
    const _Float16* __restrict__ A, const _Float16* __restrict__ W,
    const float* __restrict__ bias, float* __restrict__ Out) {
  __shared__ _Float16 As[128 * 64];
  __shared__ _Float16 Bs[64 * 64];
  int tid = threadIdx.x;
  int lane = tid & 63, wave = tid >> 6;
  int quad = lane >> 4, l15 = lane & 15;
  int wm = (wave >> 1) << 6, wn = (wave & 1) << 5;
  int m0 = blockIdx.y << 7, n0 = blockIdx.x << 6;

  f4 acc[4][2] = {};
  for (int k0 = 0; k0 < 1024; k0 += 64) {
    stage128B<4>(A + m0 * 1024 + k0, 1024, As, tid);
    stage128B<2>(W + n0 * 1024 + k0, 1024, Bs, tid);
    __syncthreads();
#pragma unroll
    for (int ks = 0; ks < 2; ++ks) {
      h8 af[4], bf[2];
#pragma unroll
      for (int i = 0; i < 4; ++i) af[i] = frag64(As, wm + i * 16 + l15, ks * 4 + quad);
#pragma unroll
      for (int i = 0; i < 2; ++i) bf[i] = frag64(Bs, wn + i * 16 + l15, ks * 4 + quad);
#pragma unroll
      for (int mi = 0; mi < 4; ++mi)
#pragma unroll
        for (int ni = 0; ni < 2; ++ni)
          acc[mi][ni] = __builtin_amdgcn_mfma_f32_16x16x32_f16(af[mi], bf[ni], acc[mi][ni], 0, 0, 0);
    }
    __syncthreads();
  }
#pragma unroll
  for (int mi = 0; mi < 4; ++mi) {
#pragma unroll
    for (int ni = 0; ni < 2; ++ni) {
      int o = n0 + wn + ni * 16 + l15;
      float bv = bias[o];
#pragma unroll
      for (int r = 0; r < 4; ++r) {
        int m = m0 + wm + mi * 16 + quad * 4 + r;
        Out[m * 1024 + o] = acc[mi][ni][r] + bv;
      }
    }
  }
}

// Flash attention, 32x32x16 MFMA. Grid (16, 32), 256 threads. R5 config.
// 4 FAT waves: qg = wave>>1 (2 x 64 qrows = 128 rows/block), parity p = wave&1.
// Each wave: 64 q-rows as 2 q-subtiles (qsub*32 + l31); every kf/vf LDS read
// feeds BOTH q-subtiles' MFMAs. Wave p computes key tiles t with t&1==p.
// Tiles staged as 64-key PAIRS (K: [64 keys][64 d] swizzle f(row), V:
// [64 d][64 keys] swizzle row&7) into 3 rotating slots, staged 2 AHEAD.
// Phase barrier `s_waitcnt vmcnt(4); s_barrier`: drains pair ph (my 4 oldest
// DMAs), pair ph+1's 4 stay in flight. Stage of pair ph+2 issued AFTER
// compute(ph) — its slot was last read at phase ph-1, sealed by barrier(ph).
// QK: S^T = K.Q^T; kf A-row m holds key = swapbits23(m), so C-layout
// (row=(reg&3)+8*(reg>>2)+4h, col=l31) gives lane h keys {s*16+h*8+j}: reg pairs
// (2i,2i+1) pack via cvt_pkrtz into PV B-operand pb[s]=pkw[4s..4s+3].
// PV: O^T = Vt.P^T (A = Vt d-rows). No online max (exp2 raw) => parity
// partials combine by plain addition through LDS at the end.
__global__ __launch_bounds__(256, 2) void attn(
    const _Float16* __restrict__ Q, const _Float16* __restrict__ Kv,
    const _Float16* __restrict__ Vt, _Float16* __restrict__ AO) {
  __shared__ _Float16 smem[6 * 4096];   // 48 KB: Ks[3] | Vs[3]
  _Float16* Ksb = smem;
  _Float16* Vsb = smem + 3 * 4096;

  int tid = threadIdx.x, lane = tid & 63, wave = tid >> 6;
  int h = lane >> 5, l31 = lane & 31;
  int p = wave & 1, qg = wave >> 1;

  // XCD-aware bijective remap (512 blocks, 8 XCDs): blocks on one XCD cover
  // 4 consecutive bh -> 2 MB K/V fits per-XCD L2 (R5: FETCH 69.7->12.3 MB).
  int flat = blockIdx.y * 16 + blockIdx.x;
  int nid = (flat & 7) * 64 + (flat >> 3);
  int bh = nid >> 4, q0 = (nid & 15) << 7;

  // qf[qsub]: B[k][n=qrow=l31], dk = ks4*16 + h*8 + j; qrows = q0+qg*64+qsub*32+l31
  const _Float16* Qb = Q + (bh * 2048 + q0 + qg * 64 + l31) * 64;
  h8 qf[2][4];
#pragma unroll
  for (int qs = 0; qs < 2; ++qs)
#pragma unroll
    for (int ks4 = 0; ks4 < 4; ++ks4)
      qf[qs][ks4] = *(const h8*)(Qb + qs * 32 * 64 + ks4 * 16 + h * 8);

  // key-row permutation: swap bits 2<->3 of C-row index
  int krow = (l31 & 19) | ((l31 & 4) << 1) | ((l31 & 8) >> 1);
  int kbase = (p * 32 + krow) * 64;   // my 32-key subtile within the 64-row pair
  int kx = (krow & 3) | ((krow >> 1) & 4);   // f(krow): matches stage_k swizzle
  int vx = l31 & 7;

  const _Float16* Kb = Kv + bh * 131072;
  const _Float16* Vb = Vt + bh * 131072;
  f16f oacc[2][2] = {};   // [qsub][dt]
  float lsum[2] = {0.f, 0.f};

  // prologue: stage pairs 0 (slot 0) and 1 (slot 1); 8 DMAs/thread outstanding
  stage_k(Kb, Ksb, tid);
  stage_v(Vb, Vsb, tid);
  stage_k(Kb + 4096, Ksb + 4096, tid);
  stage_v(Vb + 64, Vsb + 4096, tid);

  int bp = 0;   // slot of current pair = ph % 3
  for (int ph = 0; ph < 32; ++ph) {
    // Counted-vmcnt barrier: pair ph's 4 DMAs (my oldest) drained; pair ph+1's
    // 4 stay in flight across the barrier.
    if (ph < 31) {
      asm volatile("s_waitcnt vmcnt(4)\n\ts_barrier" ::: "memory");
    } else {
      asm volatile("s_waitcnt vmcnt(0)\n\ts_barrier" ::: "memory");
    }
    const _Float16* Kst = Ksb + bp * 4096;
    const _Float16* Vst = Vsb + bp * 4096;

    // QK: my 32-key subtile x 64 qrows (2 subtiles), K-dim 64 in 4 steps of 16.
    f16f sacc[2] = {};
#pragma unroll
    for (int ks4 = 0; ks4 < 4; ++ks4) {
      h8 kf = *(const h8*)(Kst + kbase + (((ks4 * 2 + h) ^ kx) << 3));
      sacc[0] = __builtin_amdgcn_mfma_f32_32x32x16_f16(kf, qf[0][ks4], sacc[0], 0, 0, 0);
      sacc[1] = __builtin_amdgcn_mfma_f32_32x32x16_f16(kf, qf[1][ks4], sacc[1], 0, 0, 0);
    }

    // P = exp2(s) raw; consecutive C regs pair into PV B-operand halves.
    u32 pkw[2][8];
#pragma unroll
    for (int qs = 0; qs < 2; ++qs) {
#pragma unroll
      for (int i = 0; i < 8; ++i) {
        float pa = __builtin_amdgcn_exp2f(sacc[qs][2 * i]);
        float pb = __builtin_amdgcn_exp2f(sacc[qs][2 * i + 1]);
        lsum[qs] += pa + pb;
        pkw[qs][i] = __builtin_bit_cast(u32, __builtin_amdgcn_cvt_pkrtz(pa, pb));
      }
    }

    // PV: O^T += Vt . P^T over 2 ksteps of 16 keys, d in 2 subtiles.
#pragma unroll
    for (int s = 0; s < 2; ++s) {
      u32x4 pw0 = {pkw[0][4 * s], pkw[0][4 * s + 1], pkw[0][4 * s + 2], pkw[0][4 * s + 3]};
      u32x4 pw1 = {pkw[1][4 * s], pkw[1][4 * s + 1], pkw[1][4 * s + 2], pkw[1][4 * s + 3]};
      h8 pb0 = __builtin_bit_cast(h8, pw0);
      h8 pb1 = __builtin_bit_cast(h8, pw1);
      int ch = (((p << 2) | (s << 1) | h) ^ vx) << 3;
#pragma unroll
      for (int dt = 0; dt < 2; ++dt) {
        h8 vf = *(const h8*)(Vst + (dt * 32 + l31) * 64 + ch);
        oacc[0][dt] = __builtin_amdgcn_mfma_f32_32x32x16_f16(vf, pb0, oacc[0][dt], 0, 0, 0);
        oacc[1][dt] = __builtin_amdgcn_mfma_f32_32x32x16_f16(vf, pb1, oacc[1][dt], 0, 0, 0);
      }
    }

    // Stage pair ph+2 into slot (bp+2)%3 (last read at phase ph-1, sealed by
    // barrier(ph) above).
    if (ph < 30) {
      int sl = bp ? bp - 1 : 2;
      stage_k(Kb + (ph + 2) * 4096, Ksb + sl * 4096, tid);
      stage_v(Vb + (ph + 2) * 64, Vsb + sl * 4096, tid);
    }
    bp = (bp == 2) ? 0 : bp + 1;
  }

  // Combine parity partials (plain addition: no-max softmax) through LDS.
  __syncthreads();   // all compute + DMA done; smem free for reuse
  float* cb = (float*)smem;   // 2 odd waves x 64 lanes x 66 floats = 33792 B
  if (p) {
    float* w = cb + (qg * 64 + lane) * 66;
#pragma unroll
    for (int qs = 0; qs < 2; ++qs)
#pragma unroll
      for (int dt = 0; dt < 2; ++dt)
#pragma unroll
        for (int i = 0; i < 16; ++i) w[(qs * 2 + dt) * 16 + i] = oacc[qs][dt][i];
    w[64] = lsum[0];
    w[65] = lsum[1];
  }
  __syncthreads();
  if (!p) {
    const float* r = cb + (qg * 64 + lane) * 66;
#pragma unroll
    for (int qs = 0; qs < 2; ++qs)
#pragma unroll
      for (int dt = 0; dt < 2; ++dt)
#pragma unroll
        for (int i = 0; i < 16; ++i) oacc[qs][dt][i] += r[(qs * 2 + dt) * 16 + i];
    lsum[0] += r[64];
    lsum[1] += r[65];

    // Epilogue: col = qrow = l31 for all oacc; rows d = dt*32 + 8*b2 + 4h + a.
    int b = bh >> 4, hh = bh & 15;
#pragma unroll
    for (int qs = 0; qs < 2; ++qs) {
      float l = lsum[qs] + __shfl_xor(lsum[qs], 32);
      float inv = 1.0f / l;
      int n = q0 + qg * 64 + qs * 32 + l31;
      _Float16* base = AO + (b * 2048 + n) * 1024 + hh * 64;
#pragma unroll
      for (int dt = 0; dt < 2; ++dt) {
#pragma unroll
        for (int b2 = 0; b2 < 4; ++b2) {
          h4 o;
#pragma unroll
          for (int a = 0; a < 4; ++a) o[a] = (_Float16)(oacc[qs][dt][b2 * 4 + a] * inv);
          *(h4*)(base + dt * 32 + b2 * 8 + h * 4) = o;
        }
      }
    }
  }
}

extern "C" void kernel_launch(void* const* d_in, const int* in_sizes, int n_in,
                              void* d_out, int out_size, void* d_ws, size_t ws_size,
                              hipStream_t stream) {
  const float* x = (const float*)d_in[0];
  const float* Wq = (const float*)d_in[1];
  const float* bq = (const float*)d_in[2];
  const float* Wk = (const float*)d_in[3];
  const float* bk = (const float*)d_in[4];
  const float* Wv = (const float*)d_in[5];
  const float* bv = (const float*)d_in[6];
  const float* Wo = (const float*)d_in[7];
  const float* bo = (const float*)d_in[8];
  float* out = (float*)d_out;

  char* w = (char*)d_ws;
  _Float16* xh  = (_Float16*)(w);                // 8 MB (reused as AO after gemm_qkv)
  _Float16* Wqh = (_Float16*)(w + (8u << 20));   // 2 MB each
  _Float16* Wkh = (_Float16*)(w + (10u << 20));
  _Float16* Wvh = (_Float16*)(w + (12u << 20));
  _Float16* Woh = (_Float16*)(w + (14u << 20));
  _Float16* Qh  = (_Float16*)(w + (16u << 20));  // 8 MB each
  _Float16* Kh  = (_Float16*)(w + (24u << 20));
  _Float16* Vth = (_Float16*)(w + (32u << 20));
  _Float16* AOh = xh;

  cvt_all<<<4096, 256, 0, stream>>>(x, Wq, Wk, Wv, Wo, xh, Wqh, Wkh, Wvh, Woh);
  gemm_qkv<<<dim3(8, 32, 3), 256, 0, stream>>>(xh, Wqh, Wkh, Wvh, bq, bk, bv, Qh, Kh, Vth);
  attn<<<dim3(16, 32), 256, 0, stream>>>(Qh, Kh, Vth, AOh);
  gemm_out<<<dim3(16, 32), 256, 0, stream>>>(AOh, Woh, bo, out);
}